// Round 2
// baseline (639.101 us; speedup 1.0000x reference)
//
#include <hip/hip_runtime.h>

#define SEQ  720
#define PRED 720
#define RANK 16
#define CTXD 128
#define HID  64
#define BATCH 256
#define ODIM  (RANK * (SEQ + PRED))   // 23040
#define ASIZE (RANK * PRED)           // 11520

typedef float v4f __attribute__((ext_vector_type(4)));

// ---------------------------------------------------------------------------
// K1: hidden[b,k] = relu(ctx[b,:] @ W1[k,:] + b1[k]);  (256, 64)
// ---------------------------------------------------------------------------
__global__ __launch_bounds__(64) void k_hidden(const float* __restrict__ ctx,
                                               const float* __restrict__ W1,
                                               const float* __restrict__ b1,
                                               float* __restrict__ hid)
{
    __shared__ alignas(16) float cl[CTXD];
    int b = blockIdx.x, k = threadIdx.x;
    cl[k]      = ctx[b * CTXD + k];
    cl[k + 64] = ctx[b * CTXD + k + 64];
    __syncthreads();
    float acc = b1[k];
    const float* wr = W1 + k * CTXD;
#pragma unroll
    for (int c = 0; c < CTXD; c += 4) {
        float4 w  = *(const float4*)(wr + c);
        float4 xv = *(const float4*)(cl + c);
        acc = fmaf(w.x, xv.x, acc);
        acc = fmaf(w.y, xv.y, acc);
        acc = fmaf(w.z, xv.z, acc);
        acc = fmaf(w.w, xv.w, acc);
    }
    hid[b * HID + k] = fmaxf(acc, 0.0f);
}

// ---------------------------------------------------------------------------
// K2: h[b,o] = hidden[b,:] @ W2[o,:] + b2[o];  (256, 23040)
// grid (ODIM/64, BATCH/64), 256 threads, 64x64 tile, 4x4 per thread.
// ---------------------------------------------------------------------------
__global__ __launch_bounds__(256) void k_hyper(const float* __restrict__ hid,
                                               const float* __restrict__ W2,
                                               const float* __restrict__ b2,
                                               float* __restrict__ h)
{
    int ot = blockIdx.x, bt = blockIdx.y;
    __shared__ alignas(16) float Hl[64 * 68];   // [b_local][k], pad 68 -> 2-way (free)
    __shared__ alignas(16) float Wl[64 * 68];   // [o_local][k]
    int tid = threadIdx.x;

    const float* hg = hid + (size_t)bt * 64 * HID;   // contiguous 4096 floats
    const float* wg = W2  + (size_t)ot * 64 * HID;   // contiguous 4096 floats
#pragma unroll
    for (int n = 0; n < 4; n++) {
        int g = tid * 4 + n * 1024;
        float4 hv = *(const float4*)(hg + g);
        float4 wv = *(const float4*)(wg + g);
        int row = g >> 6, colk = g & 63;
        *(float4*)&Hl[row * 68 + colk] = hv;
        *(float4*)&Wl[row * 68 + colk] = wv;
    }
    __syncthreads();

    int tx = tid & 15, ty = tid >> 4;
    float c[4][4];
#pragma unroll
    for (int j = 0; j < 4; j++) {
        float bv = b2[ot * 64 + j * 16 + tx];
        c[0][j] = bv; c[1][j] = bv; c[2][j] = bv; c[3][j] = bv;
    }
#pragma unroll
    for (int kc = 0; kc < HID; kc += 4) {
        float4 hv[4], wv[4];
#pragma unroll
        for (int i = 0; i < 4; i++) hv[i] = *(const float4*)&Hl[(ty * 4 + i) * 68 + kc];
#pragma unroll
        for (int j = 0; j < 4; j++) wv[j] = *(const float4*)&Wl[(j * 16 + tx) * 68 + kc];
#pragma unroll
        for (int i = 0; i < 4; i++)
#pragma unroll
            for (int j = 0; j < 4; j++) {
                c[i][j] = fmaf(hv[i].x, wv[j].x, c[i][j]);
                c[i][j] = fmaf(hv[i].y, wv[j].y, c[i][j]);
                c[i][j] = fmaf(hv[i].z, wv[j].z, c[i][j]);
                c[i][j] = fmaf(hv[i].w, wv[j].w, c[i][j]);
            }
    }
#pragma unroll
    for (int i = 0; i < 4; i++) {
        int b = bt * 64 + ty * 4 + i;
        float* hb = h + (size_t)b * ODIM + ot * 64;
#pragma unroll
        for (int j = 0; j < 4; j++)
            hb[j * 16 + tx] = c[i][j];
    }
}

// ---------------------------------------------------------------------------
// K3: W_eff[b,p,s] = W[p,s] + sum_r A[b,p,r]*B[b,r,s]; y[b,p] += W_eff*x
// grid (12 s-tiles, 12 p-tiles, 256 batches), 256 threads, 64x64 tile.
// A[b,p,r] = h[b, p*16+r];  B[b,r,s] = h[b, 11520 + r*720 + s]
// ---------------------------------------------------------------------------
#define FMA4(ci, av, bv)                 \
    ci.x = fmaf(av, bv.x, ci.x);         \
    ci.y = fmaf(av, bv.y, ci.y);         \
    ci.z = fmaf(av, bv.z, ci.z);         \
    ci.w = fmaf(av, bv.w, ci.w);

__global__ __launch_bounds__(256) void k_weff(const float* __restrict__ h,
                                              const float* __restrict__ W,
                                              const float* __restrict__ x,
                                              float* __restrict__ y,
                                              float* __restrict__ weff)
{
    int st = blockIdx.x, pt = blockIdx.y, b = blockIdx.z;
    __shared__ alignas(16) float Al[64 * 20];   // [p_local][r], pad 20 -> 2-way (free)
    __shared__ alignas(16) float Bl[16 * 64];   // [r][s_local]
    __shared__ float Yr[64 * 17];
    int tid = threadIdx.x;
    const float* hb = h + (size_t)b * ODIM;

    // A tile: rows p in [pt*64, +64), ranks 0..15 -> contiguous 1024 floats
    {
        int g = tid * 4;
        int p = pt * 64 + (g >> 4);
        float4 v = make_float4(0.f, 0.f, 0.f, 0.f);
        if (p < PRED) v = *(const float4*)(hb + pt * 1024 + g);
        *(float4*)&Al[(g >> 4) * 20 + (g & 15)] = v;
    }
    // B tile: 16 r-rows x 64 s
    {
        int r = tid >> 4, sl = (tid & 15) * 4, s = st * 64 + sl;
        float4 v = make_float4(0.f, 0.f, 0.f, 0.f);
        if (s < SEQ) v = *(const float4*)(hb + ASIZE + r * SEQ + s);
        *(float4*)&Bl[r * 64 + sl] = v;
    }
    __syncthreads();

    int tx = tid & 15, ty = tid >> 4;
    int sl = tx * 4, s = st * 64 + sl;
    bool sv = (s < SEQ);
    int p0 = pt * 64 + ty * 4;

    float4 c[4];
#pragma unroll
    for (int i = 0; i < 4; i++) c[i] = make_float4(0.f, 0.f, 0.f, 0.f);

#pragma unroll
    for (int rc = 0; rc < RANK; rc += 4) {
        float4 bb[4];
#pragma unroll
        for (int j = 0; j < 4; j++) bb[j] = *(const float4*)&Bl[(rc + j) * 64 + sl];
#pragma unroll
        for (int i = 0; i < 4; i++) {
            float4 a = *(const float4*)&Al[(ty * 4 + i) * 20 + rc];
            FMA4(c[i], a.x, bb[0]);
            FMA4(c[i], a.y, bb[1]);
            FMA4(c[i], a.z, bb[2]);
            FMA4(c[i], a.w, bb[3]);
        }
    }

    float4 xv = make_float4(0.f, 0.f, 0.f, 0.f);
    if (sv) xv = *(const float4*)(x + b * SEQ + s);

#pragma unroll
    for (int i = 0; i < 4; i++) {
        int p = p0 + i;
        float yp = 0.0f;
        if (sv && p < PRED) {
            float4 wv = *(const float4*)(W + (size_t)p * SEQ + s);
            v4f e;
            e.x = wv.x + c[i].x;
            e.y = wv.y + c[i].y;
            e.z = wv.z + c[i].z;
            e.w = wv.w + c[i].w;
            __builtin_nontemporal_store(e,
                (v4f*)(weff + (size_t)b * ((size_t)PRED * SEQ) + (size_t)p * SEQ + s));
            yp = e.x * xv.x + e.y * xv.y + e.z * xv.z + e.w * xv.w;
        }
        Yr[(ty * 4 + i) * 17 + tx] = yp;
    }
    __syncthreads();
    if (tid < 64) {
        float sum = 0.0f;
#pragma unroll
        for (int t = 0; t < 16; t++) sum += Yr[tid * 17 + t];
        int p = pt * 64 + tid;
        if (p < PRED) atomicAdd(y + (size_t)b * PRED + p, sum);
    }
}

// ---------------------------------------------------------------------------
extern "C" void kernel_launch(void* const* d_in, const int* in_sizes, int n_in,
                              void* d_out, int out_size, void* d_ws, size_t ws_size,
                              hipStream_t stream)
{
    const float* x   = (const float*)d_in[0];
    const float* ctx = (const float*)d_in[1];
    const float* W   = (const float*)d_in[2];
    const float* W1  = (const float*)d_in[3];
    const float* b1  = (const float*)d_in[4];
    const float* W2  = (const float*)d_in[5];
    const float* b2  = (const float*)d_in[6];

    float* out  = (float*)d_out;
    float* yout = out;                                  // (256, 720, 1)
    float* weff = out + (size_t)BATCH * PRED;           // (256, 720, 720)

    float* hid = (float*)d_ws;                          // 256*64 floats
    float* h   = hid + (size_t)BATCH * HID;             // 256*23040 floats

    // zero y region (W_eff kernel accumulates y via atomics)
    (void)hipMemsetAsync(yout, 0, (size_t)BATCH * PRED * sizeof(float), stream);

    k_hidden<<<dim3(BATCH), dim3(64), 0, stream>>>(ctx, W1, b1, hid);
    k_hyper<<<dim3(ODIM / 64, BATCH / 64), dim3(256), 0, stream>>>(hid, W2, b2, h);
    k_weff<<<dim3(12, 12, BATCH), dim3(256), 0, stream>>>(h, W, x, yout, weff);
}